// Round 4
// baseline (174.957 us; speedup 1.0000x reference)
//
#include <hip/hip_runtime.h>

#define K_SEL 16
#define NCAND 20   // top-20 preselect, fp64 re-rank -> exact top-16 order

// ---------------------------------------------------------------------------
// Kernel A v3: fp32 distance pass + packed-u32 top-20 preselect + fp64 re-rank
// grid: 1024 blocks = 64 windows x 16 pixel-groups; block = 1024 thr (16 waves)
// wave wv handles pixel i = (blockIdx&15)*16 + wv of window (blockIdx>>4)
// ---------------------------------------------------------------------------
__global__ __launch_bounds__(1024) void simtopk_kernel(
    const float* __restrict__ x,    // (64, 256, 32) fp32
    float* __restrict__ feat)       // (16384, 48)   [16 scores | 32 relpos]
{
    __shared__ float4 xs4[256 * 8];          // 32 KB, slot-swizzled rows
    __shared__ double rs[16][NCAND];         // re-rank scores per wave
    __shared__ int    rj[16][NCAND];         // re-rank indices per wave

    const int tid  = threadIdx.x;
    const int win  = blockIdx.x >> 4;
    const int grp  = blockIdx.x & 15;
    const int lane = tid & 63;
    const int wv   = tid >> 6;

    // stage window (coalesced float4), swizzle slot = f ^ (j&7)
    const float4* gx = reinterpret_cast<const float4*>(x + (size_t)win * 8192);
    #pragma unroll
    for (int k = 0; k < 2; ++k) {
        int v = tid + k * 1024;              // 0..2047
        int j = v >> 3, f = v & 7;
        xs4[j * 8 + (f ^ (j & 7))] = gx[v];
    }
    __syncthreads();

    const int i = grp * 16 + wv;

    // broadcast-load row i into fp32 regs (same in every lane)
    float xi[32];
    #pragma unroll
    for (int f = 0; f < 8; ++f) {
        float4 av = xs4[i * 8 + (f ^ (i & 7))];
        xi[4*f+0] = av.x; xi[4*f+1] = av.y; xi[4*f+2] = av.z; xi[4*f+3] = av.w;
    }

    // fp32 |delta| sums, packed (score_hi24 | idx8): lane owns j = lane + 64q
    unsigned int p[4];
    #pragma unroll
    for (int q = 0; q < 4; ++q) {
        const int j  = q * 64 + lane;
        const int jb = j * 8, jm = j & 7;
        float acc = 0.0f;
        #pragma unroll
        for (int f = 0; f < 8; ++f) {
            float4 bv = xs4[jb + (f ^ jm)];
            acc += fabsf(xi[4*f+0] - bv.x);
            acc += fabsf(xi[4*f+1] - bv.y);
            acc += fabsf(xi[4*f+2] - bv.z);
            acc += fabsf(xi[4*f+3] - bv.w);
        }
        p[q] = (__float_as_uint(acc) & 0xFFFFFF00u) | (unsigned int)j;
    }

    // extract top-NCAND by packed value (unique per j -> exact invalidation)
    int myj = -1;                            // lane k < NCAND gets candidate k
    for (int k = 0; k < NCAND; ++k) {
        unsigned int b = min(min(p[0], p[1]), min(p[2], p[3]));
        #pragma unroll
        for (int m = 32; m >= 1; m >>= 1)
            b = min(b, (unsigned int)__shfl_xor((int)b, m, 64));
        if (lane == k) myj = (int)(b & 0xFFu);
        #pragma unroll
        for (int q = 0; q < 4; ++q)
            if (p[q] == b) p[q] = 0xFFFFFFFFu;
    }

    // fp64 re-rank of the NCAND candidates (lanes 0..NCAND-1)
    double s = 0.0;
    if (myj >= 0) {
        const int jb = myj * 8, jm = myj & 7;
        #pragma unroll
        for (int f = 0; f < 8; ++f) {
            float4 bv = xs4[jb + (f ^ jm)];
            s += fabs((double)xi[4*f+0] - (double)bv.x);
            s += fabs((double)xi[4*f+1] - (double)bv.y);
            s += fabs((double)xi[4*f+2] - (double)bv.z);
            s += fabs((double)xi[4*f+3] - (double)bv.w);
        }
        rs[wv][lane] = s;
        rj[wv][lane] = myj;
    }
    __syncthreads();

    if (myj >= 0) {
        int rank = 0;
        #pragma unroll 4
        for (int o = 0; o < NCAND; ++o) {
            double so = rs[wv][o];
            int    jo = rj[wv][o];
            rank += (so < s || (so == s && jo < myj)) ? 1 : 0;
        }
        if (rank < K_SEL) {
            const int gp = win * 256 + i;
            feat[gp * 48 + rank] = (float)(1.0 - s * 0.03125);
            float dh = (float)((i >> 4) - (myj >> 4)) * (1.0f / 15.0f);
            float dw = (float)((i & 15) - (myj & 15)) * (1.0f / 15.0f);
            reinterpret_cast<float2*>(feat)[gp * 24 + 8 + rank] = make_float2(dh, dw);
        }
    }
}

// ---------------------------------------------------------------------------
// Kernel B v3: weights forced onto the VECTOR memory path (vmcnt) via an
// opaque-zero VGPR index, so LDS activation reads (lgkmcnt) and weight loads
// (vmcnt) are independent wait counters -> compiler can software-pipeline
// weight loads under the fma stream. Weight addresses are wave-uniform ->
// one 16B transaction per wave per load, L2-resident.
// block = 1024 thr = 64 px (lane) x 16 waves; wave owns 8 (or 4) neurons.
// ---------------------------------------------------------------------------
template<int IN4, int STR4, int LDW, int NOUT>
__device__ __forceinline__ void ffn_layer(const float4* __restrict__ in4, int px,
                                          const float* __restrict__ W,
                                          const float* __restrict__ B,
                                          int nb, int vz, float* acc)
{
    #pragma unroll
    for (int n = 0; n < NOUT; ++n) acc[n] = B[nb + n];
    #pragma unroll 2
    for (int c4 = 0; c4 < IN4; ++c4) {
        float4 a4 = in4[px * STR4 + c4];
        #pragma unroll
        for (int r = 0; r < 4; ++r) {
            // vz is an opaque 0 in a VGPR: forces global_load_dwordx4 (vmcnt)
            const float4* wr =
                reinterpret_cast<const float4*>(W + (4 * c4 + r) * LDW + nb) + vz;
            const float av = (r == 0) ? a4.x : (r == 1) ? a4.y : (r == 2) ? a4.z : a4.w;
            #pragma unroll
            for (int n4 = 0; n4 < NOUT / 4; ++n4) {
                float4 w = wr[n4];
                acc[4*n4+0] = fmaf(av, w.x, acc[4*n4+0]);
                acc[4*n4+1] = fmaf(av, w.y, acc[4*n4+1]);
                acc[4*n4+2] = fmaf(av, w.z, acc[4*n4+2]);
                acc[4*n4+3] = fmaf(av, w.w, acc[4*n4+3]);
            }
        }
    }
}

__global__ __launch_bounds__(1024, 4) void ffn_kernel(
    const float* __restrict__ x,     // (16384, 32)
    const float* __restrict__ feat,  // (16384, 48)
    const float* __restrict__ s0w, const float* __restrict__ s0b,   // 48x128
    const float* __restrict__ s1w, const float* __restrict__ s1b,   // 128x128
    const float* __restrict__ sow, const float* __restrict__ sob,   // 128x64
    const float* __restrict__ o0w, const float* __restrict__ o0b,   // 96x128
    const float* __restrict__ o1w, const float* __restrict__ o1b,   // 128x128
    const float* __restrict__ oow, const float* __restrict__ oob,   // 128x64
    float* __restrict__ out)         // (16384, 64)
{
    __shared__ float4 fs4[64 * 13];      // feat rows, 12 f4 + 1 pad
    __shared__ float4 A4[64 * 33];       // 32 f4 + 1 pad
    __shared__ float4 B4[64 * 33];

    const int tid   = threadIdx.x;
    const int px    = tid & 63;
    const int wv    = tid >> 6;                                  // 0..15
    const int nb8   = __builtin_amdgcn_readfirstlane(wv * 8);
    const int nb4   = __builtin_amdgcn_readfirstlane(wv * 4);
    const int sl8   = __builtin_amdgcn_readfirstlane(wv * 2);    // f4 slot for 8-neuron grp
    const int slsf  = __builtin_amdgcn_readfirstlane(8 + wv);    // f4 slot for sf grp
    const int pbase = blockIdx.x * 64;

    int vz;                                  // opaque zero (VGPR)
    asm volatile("v_mov_b32 %0, 0" : "=v"(vz));

    // stage feat rows (coalesced float4): 64 px x 12 f4 = 768
    if (tid < 768) {
        int p = tid / 12, f = tid - p * 12;
        fs4[p * 13 + f] = reinterpret_cast<const float4*>(feat)[(size_t)pbase * 12 + tid];
    }
    __syncthreads();

    float acc[8];

    // L1: 48 -> 128 relu   (fs4 -> A4 slots 0..31)
    ffn_layer<12, 13, 128, 8>(fs4, px, s0w, s0b, nb8, vz, acc);
    A4[px * 33 + sl8    ] = make_float4(fmaxf(acc[0],0.f), fmaxf(acc[1],0.f), fmaxf(acc[2],0.f), fmaxf(acc[3],0.f));
    A4[px * 33 + sl8 + 1] = make_float4(fmaxf(acc[4],0.f), fmaxf(acc[5],0.f), fmaxf(acc[6],0.f), fmaxf(acc[7],0.f));
    __syncthreads();

    // L2: 128 -> 128 relu  (A4 -> B4)
    ffn_layer<32, 33, 128, 8>(A4, px, s1w, s1b, nb8, vz, acc);
    B4[px * 33 + sl8    ] = make_float4(fmaxf(acc[0],0.f), fmaxf(acc[1],0.f), fmaxf(acc[2],0.f), fmaxf(acc[3],0.f));
    B4[px * 33 + sl8 + 1] = make_float4(fmaxf(acc[4],0.f), fmaxf(acc[5],0.f), fmaxf(acc[6],0.f), fmaxf(acc[7],0.f));
    __syncthreads();

    // Phase 3: stage x into A4 slots 0..7  +  L3: 128 -> 64 (sf, no relu) into A4 slots 8..23
    if (tid < 512) {
        int p = tid >> 3, f = tid & 7;
        A4[p * 33 + f] = reinterpret_cast<const float4*>(x)[(size_t)(pbase + p) * 8 + f];
    }
    ffn_layer<32, 33, 64, 4>(B4, px, sow, sob, nb4, vz, acc);
    A4[px * 33 + slsf] = make_float4(acc[0], acc[1], acc[2], acc[3]);
    __syncthreads();

    // L4: [x(32) | sf(64)] = 96 -> 128 relu  (A4 slots 0..23 -> B4); weight row = 4*c4+cc
    ffn_layer<24, 33, 128, 8>(A4, px, o0w, o0b, nb8, vz, acc);
    B4[px * 33 + sl8    ] = make_float4(fmaxf(acc[0],0.f), fmaxf(acc[1],0.f), fmaxf(acc[2],0.f), fmaxf(acc[3],0.f));
    B4[px * 33 + sl8 + 1] = make_float4(fmaxf(acc[4],0.f), fmaxf(acc[5],0.f), fmaxf(acc[6],0.f), fmaxf(acc[7],0.f));
    __syncthreads();

    // L5: 128 -> 128 relu  (B4 -> A4)
    ffn_layer<32, 33, 128, 8>(B4, px, o1w, o1b, nb8, vz, acc);
    A4[px * 33 + sl8    ] = make_float4(fmaxf(acc[0],0.f), fmaxf(acc[1],0.f), fmaxf(acc[2],0.f), fmaxf(acc[3],0.f));
    A4[px * 33 + sl8 + 1] = make_float4(fmaxf(acc[4],0.f), fmaxf(acc[5],0.f), fmaxf(acc[6],0.f), fmaxf(acc[7],0.f));
    __syncthreads();

    // L6: 128 -> 64 (+bias, no relu) -> out (float4 per thread)
    ffn_layer<32, 33, 64, 4>(A4, px, oow, oob, nb4, vz, acc);
    reinterpret_cast<float4*>(out)[(size_t)(pbase + px) * 16 + (nb4 >> 2)] =
        make_float4(acc[0], acc[1], acc[2], acc[3]);
}

extern "C" void kernel_launch(void* const* d_in, const int* in_sizes, int n_in,
                              void* d_out, int out_size, void* d_ws, size_t ws_size,
                              hipStream_t stream) {
    const float* x    = (const float*)d_in[0];
    const float* s0w  = (const float*)d_in[1];
    const float* s0b  = (const float*)d_in[2];
    const float* s1w  = (const float*)d_in[3];
    const float* s1b  = (const float*)d_in[4];
    const float* sow  = (const float*)d_in[5];
    const float* sob  = (const float*)d_in[6];
    const float* o0w  = (const float*)d_in[7];
    const float* o0b  = (const float*)d_in[8];
    const float* o1w  = (const float*)d_in[9];
    const float* o1b  = (const float*)d_in[10];
    const float* oow  = (const float*)d_in[11];
    const float* oob  = (const float*)d_in[12];
    float* feat = (float*)d_ws;                  // 16384 * 48 fp32 = 3.1 MB
    float* out  = (float*)d_out;

    simtopk_kernel<<<1024, 1024, 0, stream>>>(x, feat);
    ffn_kernel<<<256, 1024, 0, stream>>>(x, feat,
                                         s0w, s0b, s1w, s1b, sow, sob,
                                         o0w, o0b, o1w, o1b, oow, oob,
                                         out);
}

// Round 5
// 78.564 us; speedup vs baseline: 2.2269x; 2.2269x over previous
//
#include <hip/hip_runtime.h>
#include <hip/hip_bf16.h>

#define K_SEL 16
#define NCAND 20

typedef __attribute__((ext_vector_type(8))) short short8;
typedef __attribute__((ext_vector_type(4))) float f32x4;

__device__ __forceinline__ short f2bf_bits(float v) {
    union { __hip_bfloat16 b; short s; } u;
    u.b = __float2bfloat16(v);                    // RNE HW convert
    return u.s;
}
__device__ __forceinline__ float bf2f_bits(short h) {
    return __uint_as_float(((unsigned)(unsigned short)h) << 16);
}

// ---------------------------------------------------------------------------
// Kernel A (unchanged from R3): fp32 distances + packed-u32 top-20 + fp64 re-rank
// ---------------------------------------------------------------------------
__global__ __launch_bounds__(1024) void simtopk_kernel(
    const float* __restrict__ x,    // (64, 256, 32) fp32
    float* __restrict__ feat)       // (16384, 48)   [16 scores | 32 relpos]
{
    __shared__ float4 xs4[256 * 8];
    __shared__ double rs[16][NCAND];
    __shared__ int    rj[16][NCAND];

    const int tid  = threadIdx.x;
    const int win  = blockIdx.x >> 4;
    const int grp  = blockIdx.x & 15;
    const int lane = tid & 63;
    const int wv   = tid >> 6;

    const float4* gx = reinterpret_cast<const float4*>(x + (size_t)win * 8192);
    #pragma unroll
    for (int k = 0; k < 2; ++k) {
        int v = tid + k * 1024;
        int j = v >> 3, f = v & 7;
        xs4[j * 8 + (f ^ (j & 7))] = gx[v];
    }
    __syncthreads();

    const int i = grp * 16 + wv;

    float xi[32];
    #pragma unroll
    for (int f = 0; f < 8; ++f) {
        float4 av = xs4[i * 8 + (f ^ (i & 7))];
        xi[4*f+0] = av.x; xi[4*f+1] = av.y; xi[4*f+2] = av.z; xi[4*f+3] = av.w;
    }

    unsigned int p[4];
    #pragma unroll
    for (int q = 0; q < 4; ++q) {
        const int j  = q * 64 + lane;
        const int jb = j * 8, jm = j & 7;
        float acc = 0.0f;
        #pragma unroll
        for (int f = 0; f < 8; ++f) {
            float4 bv = xs4[jb + (f ^ jm)];
            acc += fabsf(xi[4*f+0] - bv.x);
            acc += fabsf(xi[4*f+1] - bv.y);
            acc += fabsf(xi[4*f+2] - bv.z);
            acc += fabsf(xi[4*f+3] - bv.w);
        }
        p[q] = (__float_as_uint(acc) & 0xFFFFFF00u) | (unsigned int)j;
    }

    int myj = -1;
    for (int k = 0; k < NCAND; ++k) {
        unsigned int b = min(min(p[0], p[1]), min(p[2], p[3]));
        #pragma unroll
        for (int m = 32; m >= 1; m >>= 1)
            b = min(b, (unsigned int)__shfl_xor((int)b, m, 64));
        if (lane == k) myj = (int)(b & 0xFFu);
        #pragma unroll
        for (int q = 0; q < 4; ++q)
            if (p[q] == b) p[q] = 0xFFFFFFFFu;
    }

    double s = 0.0;
    if (myj >= 0) {
        const int jb = myj * 8, jm = myj & 7;
        #pragma unroll
        for (int f = 0; f < 8; ++f) {
            float4 bv = xs4[jb + (f ^ jm)];
            s += fabs((double)xi[4*f+0] - (double)bv.x);
            s += fabs((double)xi[4*f+1] - (double)bv.y);
            s += fabs((double)xi[4*f+2] - (double)bv.z);
            s += fabs((double)xi[4*f+3] - (double)bv.w);
        }
        rs[wv][lane] = s;
        rj[wv][lane] = myj;
    }
    __syncthreads();

    if (myj >= 0) {
        int rank = 0;
        #pragma unroll 4
        for (int o = 0; o < NCAND; ++o) {
            double so = rs[wv][o];
            int    jo = rj[wv][o];
            rank += (so < s || (so == s && jo < myj)) ? 1 : 0;
        }
        if (rank < K_SEL) {
            const int gp = win * 256 + i;
            feat[gp * 48 + rank] = (float)(1.0 - s * 0.03125);
            float dh = (float)((i >> 4) - (myj >> 4)) * (1.0f / 15.0f);
            float dw = (float)((i & 15) - (myj & 15)) * (1.0f / 15.0f);
            reinterpret_cast<float2*>(feat)[gp * 24 + 8 + rank] = make_float2(dh, dw);
        }
    }
}

// ---------------------------------------------------------------------------
// pack_kernel: convert all 6 weight matrices into split-bf16 hi/lo planes in
// B-fragment order: idx = ((ks*N + n)*4 + kb)*8 + i  <->  W[ks*32+kb*8+i][n].
// Layers (logical sizes Kpad*N): L1 64x128, L2 128x128, L3 128x64, L4 96x128,
// L5 128x128, L6 128x64.  hi plane at woff, lo plane at woff+sz.
// ---------------------------------------------------------------------------
__global__ __launch_bounds__(256) void pack_kernel(
    const float* __restrict__ s0w, const float* __restrict__ s1w,
    const float* __restrict__ sow, const float* __restrict__ o0w,
    const float* __restrict__ o1w, const float* __restrict__ oow,
    short* __restrict__ wpack)
{
    int t = blockIdx.x * 256 + threadIdx.x;
    if (t >= 69632) return;
    int l, base;
    if      (t <  8192) { l = 0; base = 0;     }
    else if (t < 24576) { l = 1; base = 8192;  }
    else if (t < 32768) { l = 2; base = 24576; }
    else if (t < 45056) { l = 3; base = 32768; }
    else if (t < 61440) { l = 4; base = 45056; }
    else                { l = 5; base = 61440; }

    const float* W = (l == 0) ? s0w : (l == 1) ? s1w : (l == 2) ? sow
                   : (l == 3) ? o0w : (l == 4) ? o1w : oow;
    int N    = (l == 2 || l == 5) ? 64 : 128;
    int Kr   = (l == 0) ? 48 : (l == 3) ? 96 : 128;
    int woff = (l == 0) ? 0 : (l == 1) ? 16384 : (l == 2) ? 49152
             : (l == 3) ? 65536 : (l == 4) ? 90112 : 122880;
    int sz   = (l == 2 || l == 5) ? 8192 : (l == 3) ? 12288 : (l == 0) ? 8192 : 16384;

    int e = t - base;
    int i = e & 7, kb = (e >> 3) & 3, rem = e >> 5;
    int n = rem % N, ks = rem / N;
    int k = ks * 32 + kb * 8 + i;
    float v = (k < Kr) ? W[k * N + n] : 0.0f;
    short hi = f2bf_bits(v);
    float lo = v - bf2f_bits(hi);
    wpack[woff + e]      = hi;
    wpack[woff + sz + e] = f2bf_bits(lo);
}

// ---------------------------------------------------------------------------
// ffn_mfma: 6 layers via mfma_f32_16x16x32_bf16, split-bf16 (hi*hi+hi*lo+lo*hi).
// Block: 1024 thr = 16 waves; wave (mt = wv&3, ntp = wv>>2) owns M-tile mt and
// N-tiles {2ntp,2ntp+1} (or ntp for N=64).  Activations fp32 in LDS, rows of
// 512B, XOR-swizzled 16B granules (^ (px&7)<<4); A-frags read as 2x b128 and
// converted to hi/lo bf16 in-register.  Weight frags: contiguous 16B from the
// packed planes (global/L2, vmcnt path).  C/D: col=lane&15, row=(lane>>4)*4+r.
// ---------------------------------------------------------------------------
template<int K_STEPS, int NT_PER_WAVE, bool RELU, bool TO_GLOBAL>
__device__ __forceinline__ void mfma_layer(
    const char* inbuf, char* outbuf, float* gout, int pbase,
    const short* __restrict__ wpack, int woff, int sz, int N,
    const float* __restrict__ bias, int mt, int ntp, int lane, int out_col_off)
{
    f32x4 acc[NT_PER_WAVE];
    #pragma unroll
    for (int t = 0; t < NT_PER_WAVE; ++t) acc[t] = (f32x4){0.f, 0.f, 0.f, 0.f};

    const int m_a  = mt * 16 + (lane & 15);
    const int kb   = lane >> 4;
    const int swzA = (m_a & 7) << 4;

    #pragma unroll
    for (int ks = 0; ks < K_STEPS; ++ks) {
        const int boff = m_a * 512 + ks * 128 + kb * 32;
        f32x4 a0 = *(const f32x4*)(inbuf + ((boff     ) ^ swzA));
        f32x4 a1 = *(const f32x4*)(inbuf + ((boff + 16) ^ swzA));
        short8 ahi, alo;
        #pragma unroll
        for (int i2 = 0; i2 < 8; ++i2) {
            float v = (i2 < 4) ? a0[i2] : a1[i2 - 4];
            short h = f2bf_bits(v);
            ahi[i2] = h;
            alo[i2] = f2bf_bits(v - bf2f_bits(h));
        }
        #pragma unroll
        for (int tt = 0; tt < NT_PER_WAVE; ++tt) {
            const int nt = (NT_PER_WAVE == 2) ? (ntp * 2 + tt) : ntp;
            const int n  = nt * 16 + (lane & 15);
            const int wi = woff + ((ks * N + n) * 4 + kb) * 8;
            short8 whi = *(const short8*)(wpack + wi);
            short8 wlo = *(const short8*)(wpack + wi + sz);
            acc[tt] = __builtin_amdgcn_mfma_f32_16x16x32_bf16(ahi, whi, acc[tt], 0, 0, 0);
            acc[tt] = __builtin_amdgcn_mfma_f32_16x16x32_bf16(ahi, wlo, acc[tt], 0, 0, 0);
            acc[tt] = __builtin_amdgcn_mfma_f32_16x16x32_bf16(alo, whi, acc[tt], 0, 0, 0);
        }
    }

    #pragma unroll
    for (int tt = 0; tt < NT_PER_WAVE; ++tt) {
        const int nt = (NT_PER_WAVE == 2) ? (ntp * 2 + tt) : ntp;
        const int n  = nt * 16 + (lane & 15);
        const float bv = bias[n];
        #pragma unroll
        for (int r = 0; r < 4; ++r) {
            float v = acc[tt][r] + bv;
            if (RELU) v = fmaxf(v, 0.0f);
            const int pw = mt * 16 + (lane >> 4) * 4 + r;
            if (TO_GLOBAL) {
                gout[(size_t)(pbase + pw) * 64 + n] = v;
            } else {
                *(float*)(outbuf + ((pw * 512 + (out_col_off + n) * 4) ^ ((pw & 7) << 4))) = v;
            }
        }
    }
}

__global__ __launch_bounds__(1024) void ffn_mfma_kernel(
    const float* __restrict__ x,     // (16384, 32)
    const float* __restrict__ feat,  // (16384, 48)
    const short* __restrict__ wpack,
    const float* __restrict__ s0b, const float* __restrict__ s1b,
    const float* __restrict__ sob, const float* __restrict__ o0b,
    const float* __restrict__ o1b, const float* __restrict__ oob,
    float* __restrict__ out)         // (16384, 64)
{
    __shared__ __align__(16) float buf0[64 * 128];   // 32 KB
    __shared__ __align__(16) float buf1[64 * 128];   // 32 KB

    const int tid   = threadIdx.x;
    const int lane  = tid & 63;
    const int wv    = tid >> 6;
    const int mt    = wv & 3;
    const int ntp   = wv >> 2;
    const int pbase = blockIdx.x * 64;
    char* b0 = (char*)buf0;
    char* b1 = (char*)buf1;

    // stage feat (cols 0..47) + zero-pad (cols 48..63) into buf0
    if (tid < 768) {
        int p = tid / 12, c4 = tid - p * 12;
        f32x4 v = ((const f32x4*)feat)[(size_t)(pbase + p) * 12 + c4];
        *(f32x4*)(b0 + ((p * 512 + c4 * 16) ^ ((p & 7) << 4))) = v;
    } else {
        int u = tid - 768;                 // 0..255
        int p = u >> 2, j = u & 3;
        f32x4 z = (f32x4){0.f, 0.f, 0.f, 0.f};
        *(f32x4*)(b0 + ((p * 512 + (12 + j) * 16) ^ ((p & 7) << 4))) = z;
    }
    __syncthreads();

    // L1: buf0 (K=64 incl pad) -> buf1, N=128, relu
    mfma_layer<2, 2, true, false>(b0, b1, nullptr, pbase, wpack, 0, 8192, 128, s0b, mt, ntp, lane, 0);
    __syncthreads();
    // L2: buf1 -> buf0, N=128, relu
    mfma_layer<4, 2, true, false>(b1, b0, nullptr, pbase, wpack, 16384, 16384, 128, s1b, mt, ntp, lane, 0);
    __syncthreads();
    // stage x into buf1 cols 0..31  +  L3: buf0 -> buf1 cols 32..95 (sf, no relu)
    if (tid < 512) {
        int p = tid >> 3, j = tid & 7;
        f32x4 v = ((const f32x4*)x)[(size_t)(pbase + p) * 8 + j];
        *(f32x4*)(b1 + ((p * 512 + j * 16) ^ ((p & 7) << 4))) = v;
    }
    mfma_layer<4, 1, false, false>(b0, b1, nullptr, pbase, wpack, 49152, 8192, 64, sob, mt, ntp, lane, 32);
    __syncthreads();
    // L4: buf1 (K=96: x|sf) -> buf0, N=128, relu
    mfma_layer<3, 2, true, false>(b1, b0, nullptr, pbase, wpack, 65536, 12288, 128, o0b, mt, ntp, lane, 0);
    __syncthreads();
    // L5: buf0 -> buf1, N=128, relu
    mfma_layer<4, 2, true, false>(b0, b1, nullptr, pbase, wpack, 90112, 16384, 128, o1b, mt, ntp, lane, 0);
    __syncthreads();
    // L6: buf1 -> out (global), N=64, +bias
    mfma_layer<4, 1, false, true>(b1, nullptr, out, pbase, wpack, 122880, 8192, 64, oob, mt, ntp, lane, 0);
}

extern "C" void kernel_launch(void* const* d_in, const int* in_sizes, int n_in,
                              void* d_out, int out_size, void* d_ws, size_t ws_size,
                              hipStream_t stream) {
    const float* x    = (const float*)d_in[0];
    const float* s0w  = (const float*)d_in[1];
    const float* s0b  = (const float*)d_in[2];
    const float* s1w  = (const float*)d_in[3];
    const float* s1b  = (const float*)d_in[4];
    const float* sow  = (const float*)d_in[5];
    const float* sob  = (const float*)d_in[6];
    const float* o0w  = (const float*)d_in[7];
    const float* o0b  = (const float*)d_in[8];
    const float* o1w  = (const float*)d_in[9];
    const float* o1b  = (const float*)d_in[10];
    const float* oow  = (const float*)d_in[11];
    const float* oob  = (const float*)d_in[12];

    short* wpack = (short*)d_ws;                               // 278528 B
    float* feat  = (float*)((char*)d_ws + 524288);             // 16384*48*4 B
    float* out   = (float*)d_out;

    pack_kernel<<<272, 256, 0, stream>>>(s0w, s1w, sow, o0w, o1w, oow, wpack);
    simtopk_kernel<<<1024, 1024, 0, stream>>>(x, feat);
    ffn_mfma_kernel<<<256, 1024, 0, stream>>>(x, feat, wpack,
                                              s0b, s1b, sob, o0b, o1b, oob,
                                              out);
}

// Round 6
// 59.464 us; speedup vs baseline: 2.9422x; 1.3212x over previous
//
#include <hip/hip_runtime.h>
#include <hip/hip_bf16.h>

#define K_SEL 16
#define NCAND 20

typedef __attribute__((ext_vector_type(8))) short short8;
typedef __attribute__((ext_vector_type(4))) float f32x4;

__device__ __forceinline__ short f2bf_bits(float v) {
    union { __hip_bfloat16 b; short s; } u;
    u.b = __float2bfloat16(v);                    // RNE HW convert
    return u.s;
}
__device__ __forceinline__ float bf2f_bits(short h) {
    return __uint_as_float(((unsigned)(unsigned short)h) << 16);
}

// ---------------------------------------------------------------------------
// Kernel A v4: channel-major LDS (register-transpose staging), fp32 distances,
// 32-bit radix-select (ballot/popc) for exact top-20 set, fp64 re-rank.
// grid: 1024 blocks = 64 windows x 16 pixel-groups; block = 1024 thr (16 waves)
// wave wv handles pixel i = (blockIdx&15)*16 + wv of window (blockIdx>>4)
// LDS layout: element x[j][c] at word (c*64 + ((j&63) ^ ((c>>2)&7)))*4 + (j>>6)
//  -> lane reads its 4 candidates {lane,lane+64,lane+128,lane+192} as ONE b128,
//     consecutive lanes -> consecutive granules: conflict-free.
// ---------------------------------------------------------------------------
__global__ __launch_bounds__(1024) void simtopk_kernel(
    const float* __restrict__ x,    // (64, 256, 32) fp32
    float* __restrict__ feat)       // (16384, 48)   [16 scores | 32 relpos]
{
    __shared__ __align__(16) float xsT[8192];     // 32 KB transposed window
    __shared__ int    candj[16][NCAND];
    __shared__ double rs[16][NCAND];

    const int tid  = threadIdx.x;
    const int win  = blockIdx.x >> 4;
    const int grp  = blockIdx.x & 15;
    const int lane = tid & 63;
    const int wv   = tid >> 6;

    // ---- staging: threads 0..511 each load a 4j x 4c block and transpose ----
    if (tid < 512) {
        const int c4 = tid & 7, jb = tid >> 3;    // jb in [0,64)
        const float4* gx = reinterpret_cast<const float4*>(x + (size_t)win * 8192);
        float4 v0 = gx[jb * 8 + c4];              // x[jb      ][4c4..]
        float4 v1 = gx[jb * 8 + c4 + 512];        // x[jb + 64 ][4c4..]
        float4 v2 = gx[jb * 8 + c4 + 1024];       // x[jb + 128][4c4..]
        float4 v3 = gx[jb * 8 + c4 + 1536];       // x[jb + 192][4c4..]
        float4* xsT4 = reinterpret_cast<float4*>(xsT);
        const int gsw = jb ^ c4;                  // (c>>2)&7 == c4 for all 4 c's
        xsT4[(4 * c4 + 0) * 64 + gsw] = make_float4(v0.x, v1.x, v2.x, v3.x);
        xsT4[(4 * c4 + 1) * 64 + gsw] = make_float4(v0.y, v1.y, v2.y, v3.y);
        xsT4[(4 * c4 + 2) * 64 + gsw] = make_float4(v0.z, v1.z, v2.z, v3.z);
        xsT4[(4 * c4 + 3) * 64 + gsw] = make_float4(v0.w, v1.w, v2.w, v3.w);
    }

    // ---- xi row via wave-uniform scalar loads (overlaps staging) ----
    const int iu = __builtin_amdgcn_readfirstlane(grp * 16 + wv);
    const float* xrow = x + (size_t)win * 8192 + (size_t)iu * 32;
    float xi[32];
    #pragma unroll
    for (int c = 0; c < 32; ++c) xi[c] = xrow[c];

    __syncthreads();

    // ---- fp32 |delta| sums: lane owns j = lane + 64q via one b128 per channel ----
    const float4* xsT4c = reinterpret_cast<const float4*>(xsT);
    float a0 = 0.f, a1 = 0.f, a2 = 0.f, a3 = 0.f;
    #pragma unroll
    for (int c = 0; c < 32; ++c) {
        float4 a = xsT4c[c * 64 + (lane ^ ((c >> 2) & 7))];
        a0 += fabsf(a.x - xi[c]);
        a1 += fabsf(a.y - xi[c]);
        a2 += fabsf(a.z - xi[c]);
        a3 += fabsf(a.w - xi[c]);
    }
    unsigned int p[4];
    p[0] = (__float_as_uint(a0) & 0xFFFFFF00u) | (unsigned)(lane);
    p[1] = (__float_as_uint(a1) & 0xFFFFFF00u) | (unsigned)(lane + 64);
    p[2] = (__float_as_uint(a2) & 0xFFFFFF00u) | (unsigned)(lane + 128);
    p[3] = (__float_as_uint(a3) & 0xFFFFFF00u) | (unsigned)(lane + 192);

    // ---- radix-select: T = NCAND-th smallest packed key (keys unique) ----
    unsigned int T = 0;
    for (int bit = 31; bit >= 0; --bit) {
        unsigned int cand = T | (1u << bit);
        int cnt = __popcll(__ballot(p[0] < cand)) + __popcll(__ballot(p[1] < cand))
                + __popcll(__ballot(p[2] < cand)) + __popcll(__ballot(p[3] < cand));
        if (cnt < NCAND) T = cand;
    }

    // ---- compact selected (p <= T: exactly NCAND) into per-wave LDS ----
    const unsigned long long lt = (1ull << lane) - 1ull;
    int base = 0;
    #pragma unroll
    for (int q = 0; q < 4; ++q) {
        bool sel = (p[q] <= T);
        unsigned long long m = __ballot(sel);
        if (sel) candj[wv][base + __popcll(m & lt)] = q * 64 + lane;
        base += __popcll(m);
    }
    asm volatile("s_waitcnt lgkmcnt(0)" ::: "memory");

    // ---- fp64 re-rank (exact order; summation order matches prior passing code) ----
    double s = 0.0;
    int myj = -1;
    if (lane < NCAND) {
        myj = candj[wv][lane];
        const int jl = myj & 63, jq = myj >> 6;
        #pragma unroll
        for (int c = 0; c < 32; ++c) {
            float bv = xsT[(c * 64 + (jl ^ ((c >> 2) & 7))) * 4 + jq];
            s += fabs((double)xi[c] - (double)bv);
        }
        rs[wv][lane] = s;
    }
    asm volatile("s_waitcnt lgkmcnt(0)" ::: "memory");

    if (myj >= 0) {
        int rank = 0;
        #pragma unroll 4
        for (int o = 0; o < NCAND; ++o) {
            double so = rs[wv][o];
            int    jo = candj[wv][o];
            rank += (so < s || (so == s && jo < myj)) ? 1 : 0;
        }
        if (rank < K_SEL) {
            const int gp = win * 256 + iu;
            feat[gp * 48 + rank] = (float)(1.0 - s * 0.03125);
            float dh = (float)((iu >> 4) - (myj >> 4)) * (1.0f / 15.0f);
            float dw = (float)((iu & 15) - (myj & 15)) * (1.0f / 15.0f);
            reinterpret_cast<float2*>(feat)[gp * 24 + 8 + rank] = make_float2(dh, dw);
        }
    }
}

// ---------------------------------------------------------------------------
// pack_kernel: convert all 6 weight matrices into split-bf16 hi/lo planes in
// B-fragment order: idx = ((ks*N + n)*4 + kb)*8 + i  <->  W[ks*32+kb*8+i][n].
// ---------------------------------------------------------------------------
__global__ __launch_bounds__(256) void pack_kernel(
    const float* __restrict__ s0w, const float* __restrict__ s1w,
    const float* __restrict__ sow, const float* __restrict__ o0w,
    const float* __restrict__ o1w, const float* __restrict__ oow,
    short* __restrict__ wpack)
{
    int t = blockIdx.x * 256 + threadIdx.x;
    if (t >= 69632) return;
    int l, base;
    if      (t <  8192) { l = 0; base = 0;     }
    else if (t < 24576) { l = 1; base = 8192;  }
    else if (t < 32768) { l = 2; base = 24576; }
    else if (t < 45056) { l = 3; base = 32768; }
    else if (t < 61440) { l = 4; base = 45056; }
    else                { l = 5; base = 61440; }

    const float* W = (l == 0) ? s0w : (l == 1) ? s1w : (l == 2) ? sow
                   : (l == 3) ? o0w : (l == 4) ? o1w : oow;
    int N    = (l == 2 || l == 5) ? 64 : 128;
    int Kr   = (l == 0) ? 48 : (l == 3) ? 96 : 128;
    int woff = (l == 0) ? 0 : (l == 1) ? 16384 : (l == 2) ? 49152
             : (l == 3) ? 65536 : (l == 4) ? 90112 : 122880;
    int sz   = (l == 2 || l == 5) ? 8192 : (l == 3) ? 12288 : (l == 0) ? 8192 : 16384;

    int e = t - base;
    int i = e & 7, kb = (e >> 3) & 3, rem = e >> 5;
    int n = rem % N, ks = rem / N;
    int k = ks * 32 + kb * 8 + i;
    float v = (k < Kr) ? W[k * N + n] : 0.0f;
    short hi = f2bf_bits(v);
    float lo = v - bf2f_bits(hi);
    wpack[woff + e]      = hi;
    wpack[woff + sz + e] = f2bf_bits(lo);
}

// ---------------------------------------------------------------------------
// ffn_mfma (unchanged from R5): 6 layers via mfma_f32_16x16x32_bf16, split-bf16.
// ---------------------------------------------------------------------------
template<int K_STEPS, int NT_PER_WAVE, bool RELU, bool TO_GLOBAL>
__device__ __forceinline__ void mfma_layer(
    const char* inbuf, char* outbuf, float* gout, int pbase,
    const short* __restrict__ wpack, int woff, int sz, int N,
    const float* __restrict__ bias, int mt, int ntp, int lane, int out_col_off)
{
    f32x4 acc[NT_PER_WAVE];
    #pragma unroll
    for (int t = 0; t < NT_PER_WAVE; ++t) acc[t] = (f32x4){0.f, 0.f, 0.f, 0.f};

    const int m_a  = mt * 16 + (lane & 15);
    const int kb   = lane >> 4;
    const int swzA = (m_a & 7) << 4;

    #pragma unroll
    for (int ks = 0; ks < K_STEPS; ++ks) {
        const int boff = m_a * 512 + ks * 128 + kb * 32;
        f32x4 a0 = *(const f32x4*)(inbuf + ((boff     ) ^ swzA));
        f32x4 a1 = *(const f32x4*)(inbuf + ((boff + 16) ^ swzA));
        short8 ahi, alo;
        #pragma unroll
        for (int i2 = 0; i2 < 8; ++i2) {
            float v = (i2 < 4) ? a0[i2] : a1[i2 - 4];
            short h = f2bf_bits(v);
            ahi[i2] = h;
            alo[i2] = f2bf_bits(v - bf2f_bits(h));
        }
        #pragma unroll
        for (int tt = 0; tt < NT_PER_WAVE; ++tt) {
            const int nt = (NT_PER_WAVE == 2) ? (ntp * 2 + tt) : ntp;
            const int n  = nt * 16 + (lane & 15);
            const int wi = woff + ((ks * N + n) * 4 + kb) * 8;
            short8 whi = *(const short8*)(wpack + wi);
            short8 wlo = *(const short8*)(wpack + wi + sz);
            acc[tt] = __builtin_amdgcn_mfma_f32_16x16x32_bf16(ahi, whi, acc[tt], 0, 0, 0);
            acc[tt] = __builtin_amdgcn_mfma_f32_16x16x32_bf16(ahi, wlo, acc[tt], 0, 0, 0);
            acc[tt] = __builtin_amdgcn_mfma_f32_16x16x32_bf16(alo, whi, acc[tt], 0, 0, 0);
        }
    }

    #pragma unroll
    for (int tt = 0; tt < NT_PER_WAVE; ++tt) {
        const int nt = (NT_PER_WAVE == 2) ? (ntp * 2 + tt) : ntp;
        const int n  = nt * 16 + (lane & 15);
        const float bv = bias[n];
        #pragma unroll
        for (int r = 0; r < 4; ++r) {
            float v = acc[tt][r] + bv;
            if (RELU) v = fmaxf(v, 0.0f);
            const int pw = mt * 16 + (lane >> 4) * 4 + r;
            if (TO_GLOBAL) {
                gout[(size_t)(pbase + pw) * 64 + n] = v;
            } else {
                *(float*)(outbuf + ((pw * 512 + (out_col_off + n) * 4) ^ ((pw & 7) << 4))) = v;
            }
        }
    }
}

__global__ __launch_bounds__(1024) void ffn_mfma_kernel(
    const float* __restrict__ x,     // (16384, 32)
    const float* __restrict__ feat,  // (16384, 48)
    const short* __restrict__ wpack,
    const float* __restrict__ s0b, const float* __restrict__ s1b,
    const float* __restrict__ sob, const float* __restrict__ o0b,
    const float* __restrict__ o1b, const float* __restrict__ oob,
    float* __restrict__ out)         // (16384, 64)
{
    __shared__ __align__(16) float buf0[64 * 128];   // 32 KB
    __shared__ __align__(16) float buf1[64 * 128];   // 32 KB

    const int tid   = threadIdx.x;
    const int lane  = tid & 63;
    const int wv    = tid >> 6;
    const int mt    = wv & 3;
    const int ntp   = wv >> 2;
    const int pbase = blockIdx.x * 64;
    char* b0 = (char*)buf0;
    char* b1 = (char*)buf1;

    // stage feat (cols 0..47) + zero-pad (cols 48..63) into buf0
    if (tid < 768) {
        int p = tid / 12, c4 = tid - p * 12;
        f32x4 v = ((const f32x4*)feat)[(size_t)(pbase + p) * 12 + c4];
        *(f32x4*)(b0 + ((p * 512 + c4 * 16) ^ ((p & 7) << 4))) = v;
    } else {
        int u = tid - 768;                 // 0..255
        int p = u >> 2, j = u & 3;
        f32x4 z = (f32x4){0.f, 0.f, 0.f, 0.f};
        *(f32x4*)(b0 + ((p * 512 + (12 + j) * 16) ^ ((p & 7) << 4))) = z;
    }
    __syncthreads();

    // L1: buf0 (K=64 incl pad) -> buf1, N=128, relu
    mfma_layer<2, 2, true, false>(b0, b1, nullptr, pbase, wpack, 0, 8192, 128, s0b, mt, ntp, lane, 0);
    __syncthreads();
    // L2: buf1 -> buf0, N=128, relu
    mfma_layer<4, 2, true, false>(b1, b0, nullptr, pbase, wpack, 16384, 16384, 128, s1b, mt, ntp, lane, 0);
    __syncthreads();
    // stage x into buf1 cols 0..31  +  L3: buf0 -> buf1 cols 32..95 (sf, no relu)
    if (tid < 512) {
        int p = tid >> 3, j = tid & 7;
        f32x4 v = ((const f32x4*)x)[(size_t)(pbase + p) * 8 + j];
        *(f32x4*)(b1 + ((p * 512 + j * 16) ^ ((p & 7) << 4))) = v;
    }
    mfma_layer<4, 1, false, false>(b0, b1, nullptr, pbase, wpack, 49152, 8192, 64, sob, mt, ntp, lane, 32);
    __syncthreads();
    // L4: buf1 (K=96: x|sf) -> buf0, N=128, relu
    mfma_layer<3, 2, true, false>(b1, b0, nullptr, pbase, wpack, 65536, 12288, 128, o0b, mt, ntp, lane, 0);
    __syncthreads();
    // L5: buf0 -> buf1, N=128, relu
    mfma_layer<4, 2, true, false>(b0, b1, nullptr, pbase, wpack, 90112, 16384, 128, o1b, mt, ntp, lane, 0);
    __syncthreads();
    // L6: buf1 -> out (global), N=64, +bias
    mfma_layer<4, 1, false, true>(b1, nullptr, out, pbase, wpack, 122880, 8192, 64, oob, mt, ntp, lane, 0);
}

extern "C" void kernel_launch(void* const* d_in, const int* in_sizes, int n_in,
                              void* d_out, int out_size, void* d_ws, size_t ws_size,
                              hipStream_t stream) {
    const float* x    = (const float*)d_in[0];
    const float* s0w  = (const float*)d_in[1];
    const float* s0b  = (const float*)d_in[2];
    const float* s1w  = (const float*)d_in[3];
    const float* s1b  = (const float*)d_in[4];
    const float* sow  = (const float*)d_in[5];
    const float* sob  = (const float*)d_in[6];
    const float* o0w  = (const float*)d_in[7];
    const float* o0b  = (const float*)d_in[8];
    const float* o1w  = (const float*)d_in[9];
    const float* o1b  = (const float*)d_in[10];
    const float* oow  = (const float*)d_in[11];
    const float* oob  = (const float*)d_in[12];

    short* wpack = (short*)d_ws;                               // 278528 B
    float* feat  = (float*)((char*)d_ws + 524288);             // 16384*48*4 B
    float* out   = (float*)d_out;

    pack_kernel<<<272, 256, 0, stream>>>(s0w, s1w, sow, o0w, o1w, oow, wpack);
    simtopk_kernel<<<1024, 1024, 0, stream>>>(x, feat);
    ffn_mfma_kernel<<<256, 1024, 0, stream>>>(x, feat, wpack,
                                              s0b, s1b, sob, o0b, o1b, oob,
                                              out);
}